// Round 2
// baseline (247.807 us; speedup 1.0000x reference)
//
#include <hip/hip_runtime.h>
#include <math.h>

// RotamerBuilder: Kabsch alignment (rank-2 closed path in f64, no SVD) +
// NeRF atom extension + circular-RBF chi embedding.
//
// Layout (out, float32, concatenated):
//   aligned     [N*45]  at offset 0
//   next_coords [N*3]   at offset N*45
//   chi_embed   [N*288] at offset N*48
//
// Kabsch in double: eigensolving C^T C squares the condition number
// (err ~ eps*(s1/s2)^2); f32 failed at absmax 0.8 on the worst-conditioned
// residues of 400k. f64 brings that to ~1e-6 even at s2/s1 = 1e-5.

// Jacobi rotation for symmetric 3x3 in named double registers.
#define JROT(APP, AQQ, APQ, ARP, ARQ, V0P, V1P, V2P, V0Q, V1Q, V2Q)          \
  do {                                                                       \
    double apq_ = (APQ);                                                     \
    if (fabs(apq_) > 1e-300) {                                               \
      double tau_ = ((AQQ) - (APP)) / (2.0 * apq_);                          \
      double t_ = 1.0 / (fabs(tau_) + sqrt(1.0 + tau_ * tau_));              \
      if (tau_ < 0.0) t_ = -t_;                                              \
      double c_ = 1.0 / sqrt(1.0 + t_ * t_);                                 \
      double s_ = t_ * c_;                                                   \
      (APP) -= t_ * apq_;                                                    \
      (AQQ) += t_ * apq_;                                                    \
      (APQ) = 0.0;                                                           \
      double rp_ = (ARP), rq_ = (ARQ);                                       \
      (ARP) = c_ * rp_ - s_ * rq_;                                           \
      (ARQ) = s_ * rp_ + c_ * rq_;                                           \
      double x_;                                                             \
      x_ = (V0P); (V0P) = c_ * x_ - s_ * (V0Q); (V0Q) = s_ * x_ + c_ * (V0Q);\
      x_ = (V1P); (V1P) = c_ * x_ - s_ * (V1Q); (V1Q) = s_ * x_ + c_ * (V1Q);\
      x_ = (V2P); (V2P) = c_ * x_ - s_ * (V2Q); (V2Q) = s_ * x_ + c_ * (V2Q);\
    }                                                                        \
  } while (0)

__global__ __launch_bounds__(256) void kabsch_extend_kernel(
    const float* __restrict__ fixed, const float* __restrict__ mobile,
    const float* __restrict__ coords, const float* __restrict__ prev,
    const float* __restrict__ blen, const float* __restrict__ bang,
    const float* __restrict__ dihe,
    float* __restrict__ out_aligned, float* __restrict__ out_next, int N) {
  int n = blockIdx.x * 256 + threadIdx.x;
  if (n >= N) return;

  const float* fp = fixed + (size_t)n * 9;
  const float* mp = mobile + (size_t)n * 9;
  double f[3][3], m[3][3];
#pragma unroll
  for (int p = 0; p < 3; ++p)
#pragma unroll
    for (int i = 0; i < 3; ++i) {
      f[p][i] = (double)fp[p * 3 + i];
      m[p][i] = (double)mp[p * 3 + i];
    }
  double fc[3], mcm[3];
#pragma unroll
  for (int i = 0; i < 3; ++i) {
    fc[i] = (f[0][i] + f[1][i] + f[2][i]) * (1.0 / 3.0);
    mcm[i] = (m[0][i] + m[1][i] + m[2][i]) * (1.0 / 3.0);
  }
  // Cross-covariance C[i][j] = sum_p (m[p][i]-mcom[i]) * (f[p][j]-fcom[j])
  double C[3][3];
#pragma unroll
  for (int i = 0; i < 3; ++i)
#pragma unroll
    for (int j = 0; j < 3; ++j) {
      double s = 0.0;
#pragma unroll
      for (int p = 0; p < 3; ++p) s += (m[p][i] - mcm[i]) * (f[p][j] - fc[j]);
      C[i][j] = s;
    }
  // A = C^T C (symmetric)
  double a00 = C[0][0]*C[0][0] + C[1][0]*C[1][0] + C[2][0]*C[2][0];
  double a01 = C[0][0]*C[0][1] + C[1][0]*C[1][1] + C[2][0]*C[2][1];
  double a02 = C[0][0]*C[0][2] + C[1][0]*C[1][2] + C[2][0]*C[2][2];
  double a11 = C[0][1]*C[0][1] + C[1][1]*C[1][1] + C[2][1]*C[2][1];
  double a12 = C[0][1]*C[0][2] + C[1][1]*C[1][2] + C[2][1]*C[2][2];
  double a22 = C[0][2]*C[0][2] + C[1][2]*C[1][2] + C[2][2]*C[2][2];

  double v00 = 1., v01 = 0., v02 = 0.;
  double v10 = 0., v11 = 1., v12 = 0.;
  double v20 = 0., v21 = 0., v22 = 1.;
#pragma unroll
  for (int sw = 0; sw < 6; ++sw) {
    JROT(a00, a11, a01, a02, a12, v00, v10, v20, v01, v11, v21);
    JROT(a00, a22, a02, a01, a12, v00, v10, v20, v02, v12, v22);
    JROT(a11, a22, a12, a01, a02, v01, v11, v21, v02, v12, v22);
  }
  // Exclude smallest eigenpair (s3 == 0 for rank-2 C); keep the other two.
  int imin = (a00 <= a11) ? ((a00 <= a22) ? 0 : 2) : ((a11 <= a22) ? 1 : 2);
  double va0 = (imin == 0) ? v01 : v00;
  double va1 = (imin == 0) ? v11 : v10;
  double va2 = (imin == 0) ? v21 : v20;
  double vb0 = (imin == 2) ? v01 : v02;
  double vb1 = (imin == 2) ? v11 : v12;
  double vb2 = (imin == 2) ? v21 : v22;

  // u_a = normalize(C va)
  double ua0 = C[0][0]*va0 + C[0][1]*va1 + C[0][2]*va2;
  double ua1 = C[1][0]*va0 + C[1][1]*va1 + C[1][2]*va2;
  double ua2 = C[2][0]*va0 + C[2][1]*va1 + C[2][2]*va2;
  double da = ua0*ua0 + ua1*ua1 + ua2*ua2;
  double ia = 1.0 / sqrt(fmax(da, 1e-300));
  ua0 *= ia; ua1 *= ia; ua2 *= ia;
  // u_b = normalize(C vb - (ua . C vb) ua)
  double ub0 = C[0][0]*vb0 + C[0][1]*vb1 + C[0][2]*vb2;
  double ub1 = C[1][0]*vb0 + C[1][1]*vb1 + C[1][2]*vb2;
  double ub2 = C[2][0]*vb0 + C[2][1]*vb1 + C[2][2]*vb2;
  double pr = ua0*ub0 + ua1*ub1 + ua2*ub2;
  ub0 -= pr * ua0; ub1 -= pr * ua1; ub2 -= pr * ua2;
  double db = ub0*ub0 + ub1*ub1 + ub2*ub2;
  double ib = 1.0 / sqrt(fmax(db, 1e-300));
  ub0 *= ib; ub1 *= ib; ub2 *= ib;
  // third vectors by cross product -> proper rotation automatically
  double uc0 = ua1*ub2 - ua2*ub1;
  double uc1 = ua2*ub0 - ua0*ub2;
  double uc2 = ua0*ub1 - ua1*ub0;
  double vc0 = va1*vb2 - va2*vb1;
  double vc1 = va2*vb0 - va0*vb2;
  double vc2 = va0*vb1 - va1*vb0;
  // R = ua va^T + ub vb^T + uc vc^T  (== Kabsch U diag(1,1,d) W^T)
  float r00 = (float)(ua0*va0 + ub0*vb0 + uc0*vc0);
  float r01 = (float)(ua0*va1 + ub0*vb1 + uc0*vc1);
  float r02 = (float)(ua0*va2 + ub0*vb2 + uc0*vc2);
  float r10 = (float)(ua1*va0 + ub1*vb0 + uc1*vc0);
  float r11 = (float)(ua1*va1 + ub1*vb1 + uc1*vc1);
  float r12 = (float)(ua1*va2 + ub1*vb2 + uc1*vc2);
  float r20 = (float)(ua2*va0 + ub2*vb0 + uc2*vc0);
  float r21 = (float)(ua2*va1 + ub2*vb1 + uc2*vc1);
  float r22 = (float)(ua2*va2 + ub2*vb2 + uc2*vc2);
  float mc0 = (float)mcm[0], mc1 = (float)mcm[1], mc2 = (float)mcm[2];
  float fc0 = (float)fc[0], fc1 = (float)fc[1], fc2 = (float)fc[2];

  // aligned = (coords - mob_com) @ R + fixed_com
  const float* cb = coords + (size_t)n * 45;
  float* ob = out_aligned + (size_t)n * 45;
#pragma unroll
  for (int a = 0; a < 15; ++a) {
    float x = cb[a * 3 + 0] - mc0;
    float y = cb[a * 3 + 1] - mc1;
    float z = cb[a * 3 + 2] - mc2;
    ob[a * 3 + 0] = x * r00 + y * r10 + z * r20 + fc0;
    ob[a * 3 + 1] = x * r01 + y * r11 + z * r21 + fc1;
    ob[a * 3 + 2] = x * r02 + y * r12 + z * r22 + fc2;
  }

  // next_coords (NeRF extension), f32 is ample here
  const float* pp = prev + (size_t)n * 9;
  float p00 = pp[0], p01 = pp[1], p02 = pp[2];
  float p10 = pp[3], p11 = pp[4], p12 = pp[5];
  float p20 = pp[6], p21 = pp[7], p22 = pp[8];
  float bc0 = p10 - p20, bc1 = p11 - p21, bc2 = p12 - p22;
  float nb = sqrtf(bc0*bc0 + bc1*bc1 + bc2*bc2);
  float inb = 1.0f / (nb + 1e-6f);
  bc0 *= inb; bc1 *= inb; bc2 *= inb;
  float e0 = p10 - p00, e1 = p11 - p01, e2 = p12 - p02;
  float ba0 = e1 * bc2 - e2 * bc1;
  float ba1 = e2 * bc0 - e0 * bc2;
  float ba2 = e0 * bc1 - e1 * bc0;
  float nba = sqrtf(ba0*ba0 + ba1*ba1 + ba2*ba2);
  float inba = 1.0f / (nba + 1e-6f);
  ba0 *= inba; ba1 *= inba; ba2 *= inba;
  float m10 = ba1 * bc2 - ba2 * bc1;
  float m11 = ba2 * bc0 - ba0 * bc2;
  float m12 = ba0 * bc1 - ba1 * bc0;
  float L = blen[n], Aa = bang[n], D = dihe[n];
  float sA = sinf(Aa), cA = cosf(Aa), sD = sinf(D), cD = cosf(D);
  float d1 = L * cA;
  float d2 = L * sA * cD;
  float d3 = -L * sA * sD;
  out_next[(size_t)n * 3 + 0] = p20 + bc0 * d1 + m10 * d2 + ba0 * d3;
  out_next[(size_t)n * 3 + 1] = p21 + bc1 * d1 + m11 * d2 + ba1 * d3;
  out_next[(size_t)n * 3 + 2] = p22 + bc2 * d1 + m12 * d2 + ba2 * d3;
}

// chi_embed: one thread per float4 of output (72 float4 per residue:
// 4 angles x 18 float4 of 72 bins). Fully coalesced 16B stores.
__global__ __launch_bounds__(256) void chi_rbf_kernel(
    const float* __restrict__ degrees, float4* __restrict__ out_chi,
    int total4) {
  int g = blockIdx.x * 256 + threadIdx.x;
  if (g >= total4) return;
  unsigned ug = (unsigned)g;
  unsigned n = ug / 72u;
  unsigned rem = ug - n * 72u;
  unsigned k = rem / 18u;        // which angle
  unsigned q = rem - k * 18u;    // which float4 within the 72 bins
  float deg = degrees[n * 4u + k];
  float vals[4];
#pragma unroll
  for (int j = 0; j < 4; ++j) {
    float center = -180.0f + 5.0f * (float)(q * 4u + (unsigned)j);
    float t = deg - center + 180.0f;   // in (-175, 540)
    t = (t < 0.0f) ? t + 360.0f : t;
    t = (t >= 360.0f) ? t - 360.0f : t;
    float dw = t - 180.0f;
    vals[j] = expf(dw * dw * (-1.0f / 12.5f));
  }
  out_chi[g] = make_float4(vals[0], vals[1], vals[2], vals[3]);
}

extern "C" void kernel_launch(void* const* d_in, const int* in_sizes, int n_in,
                              void* d_out, int out_size, void* d_ws,
                              size_t ws_size, hipStream_t stream) {
  (void)n_in; (void)d_ws; (void)ws_size; (void)out_size;
  const float* fixed = (const float*)d_in[0];
  const float* mobile = (const float*)d_in[1];
  const float* coords = (const float*)d_in[2];
  const float* prev = (const float*)d_in[3];
  const float* blen = (const float*)d_in[4];
  const float* bang = (const float*)d_in[5];
  const float* dihe = (const float*)d_in[6];
  const float* degrees = (const float*)d_in[7];

  int N = in_sizes[0] / 9;
  float* out = (float*)d_out;
  float* out_aligned = out;                     // N*45
  float* out_next = out + (size_t)N * 45;       // N*3
  float* out_chi = out + (size_t)N * 48;        // N*288 (16B aligned: N*192 bytes)

  int blocks_a = (N + 255) / 256;
  kabsch_extend_kernel<<<blocks_a, 256, 0, stream>>>(
      fixed, mobile, coords, prev, blen, bang, dihe, out_aligned, out_next, N);

  int total4 = N * 72;
  int blocks_b = (total4 + 255) / 256;
  chi_rbf_kernel<<<blocks_b, 256, 0, stream>>>(degrees, (float4*)out_chi,
                                               total4);
}

// Round 3
// 233.734 us; speedup vs baseline: 1.0602x; 1.0602x over previous
//
#include <hip/hip_runtime.h>
#include <math.h>

// RotamerBuilder: fused single-dispatch kernel.
//   blocks [0, KB)          : Kabsch alignment (rank-2 closed path in f64)
//                             + NeRF extension, 1 thread = 1 residue
//   blocks [KB, KB+CB)      : circular-RBF chi embedding, 1 thread = 1 float4
// Fusing overlaps Kabsch's f64/VALU+latency-bound work with chi's pure
// store-BW-bound stream (different pipes -> concurrent, not serial).
//
// Layout (out, float32, concatenated):
//   aligned     [N*45]  at offset 0
//   next_coords [N*3]   at offset N*45
//   chi_embed   [N*288] at offset N*48

// Jacobi rotation for symmetric 3x3 in named double registers.
#define JROT(APP, AQQ, APQ, ARP, ARQ, V0P, V1P, V2P, V0Q, V1Q, V2Q)          \
  do {                                                                       \
    double apq_ = (APQ);                                                     \
    if (fabs(apq_) > 1e-300) {                                               \
      double tau_ = ((AQQ) - (APP)) / (2.0 * apq_);                          \
      double t_ = 1.0 / (fabs(tau_) + sqrt(1.0 + tau_ * tau_));              \
      if (tau_ < 0.0) t_ = -t_;                                              \
      double c_ = 1.0 / sqrt(1.0 + t_ * t_);                                 \
      double s_ = t_ * c_;                                                   \
      (APP) -= t_ * apq_;                                                    \
      (AQQ) += t_ * apq_;                                                    \
      (APQ) = 0.0;                                                           \
      double rp_ = (ARP), rq_ = (ARQ);                                       \
      (ARP) = c_ * rp_ - s_ * rq_;                                           \
      (ARQ) = s_ * rp_ + c_ * rq_;                                           \
      double x_;                                                             \
      x_ = (V0P); (V0P) = c_ * x_ - s_ * (V0Q); (V0Q) = s_ * x_ + c_ * (V0Q);\
      x_ = (V1P); (V1P) = c_ * x_ - s_ * (V1Q); (V1Q) = s_ * x_ + c_ * (V1Q);\
      x_ = (V2P); (V2P) = c_ * x_ - s_ * (V2Q); (V2Q) = s_ * x_ + c_ * (V2Q);\
    }                                                                        \
  } while (0)

__device__ __forceinline__ void kabsch_residue(
    const float* __restrict__ fixed, const float* __restrict__ mobile,
    const float* __restrict__ coords, const float* __restrict__ prev,
    const float* __restrict__ blen, const float* __restrict__ bang,
    const float* __restrict__ dihe,
    float* __restrict__ out_aligned, float* __restrict__ out_next, int n) {
  const float* fp = fixed + (size_t)n * 9;
  const float* mp = mobile + (size_t)n * 9;
  double f[3][3], m[3][3];
#pragma unroll
  for (int p = 0; p < 3; ++p)
#pragma unroll
    for (int i = 0; i < 3; ++i) {
      f[p][i] = (double)fp[p * 3 + i];
      m[p][i] = (double)mp[p * 3 + i];
    }
  double fc[3], mcm[3];
#pragma unroll
  for (int i = 0; i < 3; ++i) {
    fc[i] = (f[0][i] + f[1][i] + f[2][i]) * (1.0 / 3.0);
    mcm[i] = (m[0][i] + m[1][i] + m[2][i]) * (1.0 / 3.0);
  }
  double C[3][3];
#pragma unroll
  for (int i = 0; i < 3; ++i)
#pragma unroll
    for (int j = 0; j < 3; ++j) {
      double s = 0.0;
#pragma unroll
      for (int p = 0; p < 3; ++p) s += (m[p][i] - mcm[i]) * (f[p][j] - fc[j]);
      C[i][j] = s;
    }
  double a00 = C[0][0]*C[0][0] + C[1][0]*C[1][0] + C[2][0]*C[2][0];
  double a01 = C[0][0]*C[0][1] + C[1][0]*C[1][1] + C[2][0]*C[2][1];
  double a02 = C[0][0]*C[0][2] + C[1][0]*C[1][2] + C[2][0]*C[2][2];
  double a11 = C[0][1]*C[0][1] + C[1][1]*C[1][1] + C[2][1]*C[2][1];
  double a12 = C[0][1]*C[0][2] + C[1][1]*C[1][2] + C[2][1]*C[2][2];
  double a22 = C[0][2]*C[0][2] + C[1][2]*C[1][2] + C[2][2]*C[2][2];

  double v00 = 1., v01 = 0., v02 = 0.;
  double v10 = 0., v11 = 1., v12 = 0.;
  double v20 = 0., v21 = 0., v22 = 1.;
#pragma unroll
  for (int sw = 0; sw < 6; ++sw) {
    JROT(a00, a11, a01, a02, a12, v00, v10, v20, v01, v11, v21);
    JROT(a00, a22, a02, a01, a12, v00, v10, v20, v02, v12, v22);
    JROT(a11, a22, a12, a01, a02, v01, v11, v21, v02, v12, v22);
  }
  int imin = (a00 <= a11) ? ((a00 <= a22) ? 0 : 2) : ((a11 <= a22) ? 1 : 2);
  double va0 = (imin == 0) ? v01 : v00;
  double va1 = (imin == 0) ? v11 : v10;
  double va2 = (imin == 0) ? v21 : v20;
  double vb0 = (imin == 2) ? v01 : v02;
  double vb1 = (imin == 2) ? v11 : v12;
  double vb2 = (imin == 2) ? v21 : v22;

  double ua0 = C[0][0]*va0 + C[0][1]*va1 + C[0][2]*va2;
  double ua1 = C[1][0]*va0 + C[1][1]*va1 + C[1][2]*va2;
  double ua2 = C[2][0]*va0 + C[2][1]*va1 + C[2][2]*va2;
  double da = ua0*ua0 + ua1*ua1 + ua2*ua2;
  double ia = 1.0 / sqrt(fmax(da, 1e-300));
  ua0 *= ia; ua1 *= ia; ua2 *= ia;
  double ub0 = C[0][0]*vb0 + C[0][1]*vb1 + C[0][2]*vb2;
  double ub1 = C[1][0]*vb0 + C[1][1]*vb1 + C[1][2]*vb2;
  double ub2 = C[2][0]*vb0 + C[2][1]*vb1 + C[2][2]*vb2;
  double pr = ua0*ub0 + ua1*ub1 + ua2*ub2;
  ub0 -= pr * ua0; ub1 -= pr * ua1; ub2 -= pr * ua2;
  double db = ub0*ub0 + ub1*ub1 + ub2*ub2;
  double ib = 1.0 / sqrt(fmax(db, 1e-300));
  ub0 *= ib; ub1 *= ib; ub2 *= ib;
  double uc0 = ua1*ub2 - ua2*ub1;
  double uc1 = ua2*ub0 - ua0*ub2;
  double uc2 = ua0*ub1 - ua1*ub0;
  double vc0 = va1*vb2 - va2*vb1;
  double vc1 = va2*vb0 - va0*vb2;
  double vc2 = va0*vb1 - va1*vb0;
  float r00 = (float)(ua0*va0 + ub0*vb0 + uc0*vc0);
  float r01 = (float)(ua0*va1 + ub0*vb1 + uc0*vc1);
  float r02 = (float)(ua0*va2 + ub0*vb2 + uc0*vc2);
  float r10 = (float)(ua1*va0 + ub1*vb0 + uc1*vc0);
  float r11 = (float)(ua1*va1 + ub1*vb1 + uc1*vc1);
  float r12 = (float)(ua1*va2 + ub1*vb2 + uc1*vc2);
  float r20 = (float)(ua2*va0 + ub2*vb0 + uc2*vc0);
  float r21 = (float)(ua2*va1 + ub2*vb1 + uc2*vc1);
  float r22 = (float)(ua2*va2 + ub2*vb2 + uc2*vc2);
  float mc0 = (float)mcm[0], mc1 = (float)mcm[1], mc2 = (float)mcm[2];
  float fc0 = (float)fc[0], fc1 = (float)fc[1], fc2 = (float)fc[2];

  const float* cb = coords + (size_t)n * 45;
  float* ob = out_aligned + (size_t)n * 45;
#pragma unroll
  for (int a = 0; a < 15; ++a) {
    float x = cb[a * 3 + 0] - mc0;
    float y = cb[a * 3 + 1] - mc1;
    float z = cb[a * 3 + 2] - mc2;
    ob[a * 3 + 0] = x * r00 + y * r10 + z * r20 + fc0;
    ob[a * 3 + 1] = x * r01 + y * r11 + z * r21 + fc1;
    ob[a * 3 + 2] = x * r02 + y * r12 + z * r22 + fc2;
  }

  const float* pp = prev + (size_t)n * 9;
  float p00 = pp[0], p01 = pp[1], p02 = pp[2];
  float p10 = pp[3], p11 = pp[4], p12 = pp[5];
  float p20 = pp[6], p21 = pp[7], p22 = pp[8];
  float bc0 = p10 - p20, bc1 = p11 - p21, bc2 = p12 - p22;
  float nb = sqrtf(bc0*bc0 + bc1*bc1 + bc2*bc2);
  float inb = 1.0f / (nb + 1e-6f);
  bc0 *= inb; bc1 *= inb; bc2 *= inb;
  float e0 = p10 - p00, e1 = p11 - p01, e2 = p12 - p02;
  float ba0 = e1 * bc2 - e2 * bc1;
  float ba1 = e2 * bc0 - e0 * bc2;
  float ba2 = e0 * bc1 - e1 * bc0;
  float nba = sqrtf(ba0*ba0 + ba1*ba1 + ba2*ba2);
  float inba = 1.0f / (nba + 1e-6f);
  ba0 *= inba; ba1 *= inba; ba2 *= inba;
  float m10 = ba1 * bc2 - ba2 * bc1;
  float m11 = ba2 * bc0 - ba0 * bc2;
  float m12 = ba0 * bc1 - ba1 * bc0;
  float L = blen[n], Aa = bang[n], D = dihe[n];
  float sA = sinf(Aa), cA = cosf(Aa), sD = sinf(D), cD = cosf(D);
  float d1 = L * cA;
  float d2 = L * sA * cD;
  float d3 = -L * sA * sD;
  out_next[(size_t)n * 3 + 0] = p20 + bc0 * d1 + m10 * d2 + ba0 * d3;
  out_next[(size_t)n * 3 + 1] = p21 + bc1 * d1 + m11 * d2 + ba1 * d3;
  out_next[(size_t)n * 3 + 2] = p22 + bc2 * d1 + m12 * d2 + ba2 * d3;
}

__global__ __launch_bounds__(256) void rotamer_fused_kernel(
    const float* __restrict__ fixed, const float* __restrict__ mobile,
    const float* __restrict__ coords, const float* __restrict__ prev,
    const float* __restrict__ blen, const float* __restrict__ bang,
    const float* __restrict__ dihe, const float* __restrict__ degrees,
    float* __restrict__ out_aligned, float* __restrict__ out_next,
    float4* __restrict__ out_chi, int N, int KB, int total4) {
  int b = blockIdx.x;
  if (b < KB) {
    int n = b * 256 + threadIdx.x;
    if (n < N)
      kabsch_residue(fixed, mobile, coords, prev, blen, bang, dihe,
                     out_aligned, out_next, n);
    return;
  }
  int g = (b - KB) * 256 + threadIdx.x;
  if (g >= total4) return;
  unsigned ug = (unsigned)g;
  unsigned n = ug / 72u;         // magic-mul
  unsigned rem = ug - n * 72u;
  unsigned k = rem / 18u;        // which angle
  unsigned q = rem - k * 18u;    // which float4 within the 72 bins
  float deg = degrees[n * 4u + k];
  float base = (float)(q * 20u) - 180.0f;  // center of bin q*4
  float vals[4];
#pragma unroll
  for (int j = 0; j < 4; ++j) {
    float center = base + 5.0f * (float)j;
    float t = deg - center + 180.0f;   // in (-175, 540)
    t = (t < 0.0f) ? t + 360.0f : t;
    t = (t >= 360.0f) ? t - 360.0f : t;
    float dw = t - 180.0f;
    vals[j] = __expf(dw * dw * (-1.0f / 12.5f));  // v_exp_f32 path
  }
  out_chi[g] = make_float4(vals[0], vals[1], vals[2], vals[3]);
}

extern "C" void kernel_launch(void* const* d_in, const int* in_sizes, int n_in,
                              void* d_out, int out_size, void* d_ws,
                              size_t ws_size, hipStream_t stream) {
  (void)n_in; (void)d_ws; (void)ws_size; (void)out_size;
  const float* fixed = (const float*)d_in[0];
  const float* mobile = (const float*)d_in[1];
  const float* coords = (const float*)d_in[2];
  const float* prev = (const float*)d_in[3];
  const float* blen = (const float*)d_in[4];
  const float* bang = (const float*)d_in[5];
  const float* dihe = (const float*)d_in[6];
  const float* degrees = (const float*)d_in[7];

  int N = in_sizes[0] / 9;
  float* out = (float*)d_out;
  float* out_aligned = out;                     // N*45
  float* out_next = out + (size_t)N * 45;       // N*3
  float* out_chi = out + (size_t)N * 48;        // N*288 (16B aligned)

  int KB = (N + 255) / 256;                     // kabsch blocks (first)
  int total4 = N * 72;
  int CB = (total4 + 255) / 256;                // chi blocks
  rotamer_fused_kernel<<<KB + CB, 256, 0, stream>>>(
      fixed, mobile, coords, prev, blen, bang, dihe, degrees,
      out_aligned, out_next, (float4*)out_chi, N, KB, total4);
}

// Round 4
// 130.732 us; speedup vs baseline: 1.8955x; 1.7879x over previous
//
#include <hip/hip_runtime.h>
#include <math.h>

// RotamerBuilder: fused single-dispatch kernel.
//   blocks [0, KB)     : Kabsch alignment + NeRF extension, 1 thread/residue
//   blocks [KB, KB+CB) : circular-RBF chi embedding, 1 thread = 1 float4
//
// Kabsch via rank-2 closed form (NO iterative Jacobi, no f64 div/sqrt chains
// beyond 6 total): null vector from best row-cross of C, then one exact 2x2
// Jacobi rotation on the deflated Gram matrix. f64 algebra, ~30 live doubles
// (the old 18-unrolled-JROT f64 path plausibly spilled to scratch and was the
// ~130us phase).
//
// Layout (out, float32, concatenated):
//   aligned     [N*45]  at offset 0
//   next_coords [N*3]   at offset N*45
//   chi_embed   [N*288] at offset N*48

typedef float f32x4 __attribute__((ext_vector_type(4)));

__device__ __forceinline__ void kabsch_residue(
    const float* __restrict__ fixed, const float* __restrict__ mobile,
    const float* __restrict__ coords, const float* __restrict__ prev,
    const float* __restrict__ blen, const float* __restrict__ bang,
    const float* __restrict__ dihe,
    float* __restrict__ out_aligned, float* __restrict__ out_next, int n) {
  const float* fp = fixed + (size_t)n * 9;
  const float* mp = mobile + (size_t)n * 9;
  double f[3][3], m[3][3];
#pragma unroll
  for (int p = 0; p < 3; ++p)
#pragma unroll
    for (int i = 0; i < 3; ++i) {
      f[p][i] = (double)fp[p * 3 + i];
      m[p][i] = (double)mp[p * 3 + i];
    }
  double fc[3], mcm[3];
#pragma unroll
  for (int i = 0; i < 3; ++i) {
    fc[i] = (f[0][i] + f[1][i] + f[2][i]) * (1.0 / 3.0);
    mcm[i] = (m[0][i] + m[1][i] + m[2][i]) * (1.0 / 3.0);
  }
  // Cross-covariance C[i][j] = sum_p (m[p][i]-mcom[i]) * (f[p][j]-fcom[j])
  double C[3][3];
#pragma unroll
  for (int i = 0; i < 3; ++i)
#pragma unroll
    for (int j = 0; j < 3; ++j) {
      double s = 0.0;
#pragma unroll
      for (int p = 0; p < 3; ++p) s += (m[p][i] - mcm[i]) * (f[p][j] - fc[j]);
      C[i][j] = s;
    }

  // --- null vector v3 = best row-cross of C (C has rank <= 2) ---
  double x01 = C[0][1]*C[1][2] - C[0][2]*C[1][1];
  double y01 = C[0][2]*C[1][0] - C[0][0]*C[1][2];
  double z01 = C[0][0]*C[1][1] - C[0][1]*C[1][0];
  double x02 = C[0][1]*C[2][2] - C[0][2]*C[2][1];
  double y02 = C[0][2]*C[2][0] - C[0][0]*C[2][2];
  double z02 = C[0][0]*C[2][1] - C[0][1]*C[2][0];
  double x12 = C[1][1]*C[2][2] - C[1][2]*C[2][1];
  double y12 = C[1][2]*C[2][0] - C[1][0]*C[2][2];
  double z12 = C[1][0]*C[2][1] - C[1][1]*C[2][0];
  double n01 = x01*x01 + y01*y01 + z01*z01;
  double n02 = x02*x02 + y02*y02 + z02*z02;
  double n12 = x12*x12 + y12*y12 + z12*z12;
  double vx = x01, vy = y01, vz = z01, nn = n01;
  if (n02 > nn) { vx = x02; vy = y02; vz = z02; nn = n02; }
  if (n12 > nn) { vx = x12; vy = y12; vz = z12; nn = n12; }
  double invn = 1.0 / sqrt(fmax(nn, 1e-300));
  vx *= invn; vy *= invn; vz *= invn;

  // --- orthonormal basis {w1, w2} of the plane perpendicular to v3 ---
  double av0 = fabs(vx), av1 = fabs(vy), av2 = fabs(vz);
  double w10, w11, w12;
  if (av0 <= av1 && av0 <= av2) {
    w10 = 1.0 - vx*vx; w11 = -vx*vy; w12 = -vx*vz;
  } else if (av1 <= av2) {
    w10 = -vy*vx; w11 = 1.0 - vy*vy; w12 = -vy*vz;
  } else {
    w10 = -vz*vx; w11 = -vz*vy; w12 = 1.0 - vz*vz;
  }
  double iw = 1.0 / sqrt(fmax(w10*w10 + w11*w11 + w12*w12, 1e-300));
  w10 *= iw; w11 *= iw; w12 *= iw;
  double w20 = vy*w12 - vz*w11;
  double w21 = vz*w10 - vx*w12;
  double w22 = vx*w11 - vy*w10;

  // --- b_i = C w_i ; Gram 2x2 ; one exact Jacobi rotation ---
  double b10 = C[0][0]*w10 + C[0][1]*w11 + C[0][2]*w12;
  double b11 = C[1][0]*w10 + C[1][1]*w11 + C[1][2]*w12;
  double b12 = C[2][0]*w10 + C[2][1]*w11 + C[2][2]*w12;
  double b20 = C[0][0]*w20 + C[0][1]*w21 + C[0][2]*w22;
  double b21 = C[1][0]*w20 + C[1][1]*w21 + C[1][2]*w22;
  double b22 = C[2][0]*w20 + C[2][1]*w21 + C[2][2]*w22;
  double g00 = b10*b10 + b11*b11 + b12*b12;
  double g01 = b10*b20 + b11*b21 + b12*b22;
  double g11 = b20*b20 + b21*b21 + b22*b22;
  double c, s;
  if (fabs(g01) > 1e-300) {
    double tau = (g11 - g00) / (2.0 * g01);
    double tt = 1.0 / (fabs(tau) + sqrt(1.0 + tau * tau));
    if (tau < 0.0) tt = -tt;
    c = 1.0 / sqrt(1.0 + tt * tt);
    s = tt * c;
  } else {
    c = 1.0; s = 0.0;
  }
  // true singular vectors (order/sign irrelevant for the outer-product sum)
  double va0 = c*w10 - s*w20, va1 = c*w11 - s*w21, va2 = c*w12 - s*w22;
  double vb0 = s*w10 + c*w20, vb1 = s*w11 + c*w21, vb2 = s*w12 + c*w22;
  double Ca0 = c*b10 - s*b20, Ca1 = c*b11 - s*b21, Ca2 = c*b12 - s*b22;
  double Cb0 = s*b10 + c*b20, Cb1 = s*b11 + c*b21, Cb2 = s*b12 + c*b22;

  double ia = 1.0 / sqrt(fmax(Ca0*Ca0 + Ca1*Ca1 + Ca2*Ca2, 1e-300));
  double ua0 = Ca0 * ia, ua1 = Ca1 * ia, ua2 = Ca2 * ia;
  double pr = ua0*Cb0 + ua1*Cb1 + ua2*Cb2;
  double ub0 = Cb0 - pr*ua0, ub1 = Cb1 - pr*ua1, ub2 = Cb2 - pr*ua2;
  double ib = 1.0 / sqrt(fmax(ub0*ub0 + ub1*ub1 + ub2*ub2, 1e-300));
  ub0 *= ib; ub1 *= ib; ub2 *= ib;
  double uc0 = ua1*ub2 - ua2*ub1;
  double uc1 = ua2*ub0 - ua0*ub2;
  double uc2 = ua0*ub1 - ua1*ub0;
  double vc0 = va1*vb2 - va2*vb1;
  double vc1 = va2*vb0 - va0*vb2;
  double vc2 = va0*vb1 - va1*vb0;
  // R = ua va^T + ub vb^T + uc vc^T  (== Kabsch U diag(1,1,det) W^T)
  float r00 = (float)(ua0*va0 + ub0*vb0 + uc0*vc0);
  float r01 = (float)(ua0*va1 + ub0*vb1 + uc0*vc1);
  float r02 = (float)(ua0*va2 + ub0*vb2 + uc0*vc2);
  float r10 = (float)(ua1*va0 + ub1*vb0 + uc1*vc0);
  float r11 = (float)(ua1*va1 + ub1*vb1 + uc1*vc1);
  float r12 = (float)(ua1*va2 + ub1*vb2 + uc1*vc2);
  float r20 = (float)(ua2*va0 + ub2*vb0 + uc2*vc0);
  float r21 = (float)(ua2*va1 + ub2*vb1 + uc2*vc1);
  float r22 = (float)(ua2*va2 + ub2*vb2 + uc2*vc2);
  float mc0 = (float)mcm[0], mc1 = (float)mcm[1], mc2 = (float)mcm[2];
  float fc0 = (float)fc[0], fc1 = (float)fc[1], fc2 = (float)fc[2];

  // aligned = (coords - mob_com) @ R + fixed_com
  const float* cb = coords + (size_t)n * 45;
  float* ob = out_aligned + (size_t)n * 45;
#pragma unroll
  for (int a = 0; a < 15; ++a) {
    float x = cb[a * 3 + 0] - mc0;
    float y = cb[a * 3 + 1] - mc1;
    float z = cb[a * 3 + 2] - mc2;
    ob[a * 3 + 0] = x * r00 + y * r10 + z * r20 + fc0;
    ob[a * 3 + 1] = x * r01 + y * r11 + z * r21 + fc1;
    ob[a * 3 + 2] = x * r02 + y * r12 + z * r22 + fc2;
  }

  // next_coords (NeRF extension), f32
  const float* pp = prev + (size_t)n * 9;
  float p00 = pp[0], p01 = pp[1], p02 = pp[2];
  float p10 = pp[3], p11 = pp[4], p12 = pp[5];
  float p20 = pp[6], p21 = pp[7], p22 = pp[8];
  float bc0 = p10 - p20, bc1 = p11 - p21, bc2 = p12 - p22;
  float nb = sqrtf(bc0*bc0 + bc1*bc1 + bc2*bc2);
  float inb = 1.0f / (nb + 1e-6f);
  bc0 *= inb; bc1 *= inb; bc2 *= inb;
  float e0 = p10 - p00, e1 = p11 - p01, e2 = p12 - p02;
  float ba0 = e1 * bc2 - e2 * bc1;
  float ba1 = e2 * bc0 - e0 * bc2;
  float ba2 = e0 * bc1 - e1 * bc0;
  float nba = sqrtf(ba0*ba0 + ba1*ba1 + ba2*ba2);
  float inba = 1.0f / (nba + 1e-6f);
  ba0 *= inba; ba1 *= inba; ba2 *= inba;
  float m10 = ba1 * bc2 - ba2 * bc1;
  float m11 = ba2 * bc0 - ba0 * bc2;
  float m12 = ba0 * bc1 - ba1 * bc0;
  float L = blen[n], Aa = bang[n], D = dihe[n];
  float sA = sinf(Aa), cA = cosf(Aa), sD = sinf(D), cD = cosf(D);
  float d1 = L * cA;
  float d2 = L * sA * cD;
  float d3 = -L * sA * sD;
  out_next[(size_t)n * 3 + 0] = p20 + bc0 * d1 + m10 * d2 + ba0 * d3;
  out_next[(size_t)n * 3 + 1] = p21 + bc1 * d1 + m11 * d2 + ba1 * d3;
  out_next[(size_t)n * 3 + 2] = p22 + bc2 * d1 + m12 * d2 + ba2 * d3;
}

__global__ __launch_bounds__(256) void rotamer_fused_kernel(
    const float* __restrict__ fixed, const float* __restrict__ mobile,
    const float* __restrict__ coords, const float* __restrict__ prev,
    const float* __restrict__ blen, const float* __restrict__ bang,
    const float* __restrict__ dihe, const float* __restrict__ degrees,
    float* __restrict__ out_aligned, float* __restrict__ out_next,
    f32x4* __restrict__ out_chi, int N, int KB, int total4) {
  int b = blockIdx.x;
  if (b < KB) {
    int n = b * 256 + threadIdx.x;
    if (n < N)
      kabsch_residue(fixed, mobile, coords, prev, blen, bang, dihe,
                     out_aligned, out_next, n);
    return;
  }
  int g = (b - KB) * 256 + threadIdx.x;
  if (g >= total4) return;
  unsigned ug = (unsigned)g;
  unsigned n = ug / 72u;         // magic-mul
  unsigned rem = ug - n * 72u;
  unsigned k = rem / 18u;        // which angle
  unsigned q = rem - k * 18u;    // which float4 within the 72 bins
  float deg = degrees[n * 4u + k];
  float base = (float)(q * 20u) - 180.0f;
  f32x4 v;
#pragma unroll
  for (int j = 0; j < 4; ++j) {
    float center = base + 5.0f * (float)j;
    float t = deg - center + 180.0f;   // in (-175, 540)
    t = (t < 0.0f) ? t + 360.0f : t;
    t = (t >= 360.0f) ? t - 360.0f : t;
    float dw = t - 180.0f;
    v[j] = __expf(dw * dw * (-1.0f / 12.5f));  // v_exp_f32 path
  }
  __builtin_nontemporal_store(v, &out_chi[g]);  // streaming full-line store
}

extern "C" void kernel_launch(void* const* d_in, const int* in_sizes, int n_in,
                              void* d_out, int out_size, void* d_ws,
                              size_t ws_size, hipStream_t stream) {
  (void)n_in; (void)d_ws; (void)ws_size; (void)out_size;
  const float* fixed = (const float*)d_in[0];
  const float* mobile = (const float*)d_in[1];
  const float* coords = (const float*)d_in[2];
  const float* prev = (const float*)d_in[3];
  const float* blen = (const float*)d_in[4];
  const float* bang = (const float*)d_in[5];
  const float* dihe = (const float*)d_in[6];
  const float* degrees = (const float*)d_in[7];

  int N = in_sizes[0] / 9;
  float* out = (float*)d_out;
  float* out_aligned = out;                     // N*45
  float* out_next = out + (size_t)N * 45;       // N*3
  float* out_chi = out + (size_t)N * 48;        // N*288 (16B aligned)

  int KB = (N + 255) / 256;                     // kabsch blocks (first)
  int total4 = N * 72;
  int CB = (total4 + 255) / 256;                // chi blocks
  rotamer_fused_kernel<<<KB + CB, 256, 0, stream>>>(
      fixed, mobile, coords, prev, blen, bang, dihe, degrees,
      out_aligned, out_next, (f32x4*)out_chi, N, KB, total4);
}